// Round 7
// baseline (192.177 us; speedup 1.0000x reference)
//
#include <hip/hip_runtime.h>
#include <hip/hip_bf16.h>

typedef __bf16 bf16_t;
typedef __bf16 bf16x4 __attribute__((ext_vector_type(4)));
typedef __bf16 bf16x8 __attribute__((ext_vector_type(8)));
typedef float  f32x4  __attribute__((ext_vector_type(4)));
typedef float  f32x8  __attribute__((ext_vector_type(8)));
typedef unsigned int u32;
typedef u32 u32x4 __attribute__((ext_vector_type(4)));

#define EMBED 512
#define NH    8
#define HD    64
#define SEQ   2048
#define MTOT  8192
#define SCQ   0.18033688011112042f   // log2(e) / sqrt(64), folded into Q

__device__ __forceinline__ float gelu_f(float x) {
    return 0.5f * x * (1.0f + erff(x * 0.7071067811865475f));
}

__device__ __forceinline__ f32x4 mfma16(bf16x8 a, bf16x8 b, f32x4 c) {
    return __builtin_amdgcn_mfma_f32_16x16x32_bf16(a, b, c, 0, 0, 0);
}

// Raw barrier: LDS-write visibility only (lgkmcnt(0)), NO vmcnt drain.
__device__ __forceinline__ void barrier_nodrain() {
    asm volatile("s_waitcnt lgkmcnt(0)" ::: "memory");
    __builtin_amdgcn_s_barrier();
    asm volatile("" ::: "memory");
}
// Plain barrier (reads already consumed; orders buffer reuse).
__device__ __forceinline__ void barrier_plain() {
    __builtin_amdgcn_s_barrier();
    asm volatile("" ::: "memory");
}

// Async global->LDS DMA, 16 B per lane. Dest is WAVE-UNIFORM base + lane*16.
__device__ __forceinline__ void gload16(const bf16_t* g, bf16_t* l) {
    __builtin_amdgcn_global_load_lds(
        (const __attribute__((address_space(1))) void*)g,
        (__attribute__((address_space(3))) void*)l, 16, 0, 0);
}

// T12 primitives (flash): pack 2 f32 -> 2 bf16, cross-lane register swaps.
__device__ __forceinline__ u32 cvtpk_bf16(float lo, float hi) {
    u32 r;
    asm("v_cvt_pk_bf16_f32 %0, %1, %2" : "=v"(r) : "v"(lo), "v"(hi));
    return r;
}
__device__ __forceinline__ void swap32(u32& a, u32& b) {
    asm volatile("v_permlane32_swap_b32 %0, %1" : "+v"(a), "+v"(b));
}
__device__ __forceinline__ void swap16(u32& a, u32& b) {
    asm volatile("v_permlane16_swap_b32 %0, %1" : "+v"(a), "+v"(b));
}

// ---------------------------------------------------------------------------
// Pre-convert fp32 -> bf16: x (16 segments of 256K elems) + Wq/Wk/Wv.
// grid (64, 19), 256 thr, 16 elems/thr.
// ---------------------------------------------------------------------------
__global__ __launch_bounds__(256)
void convert_kernel(const float* __restrict__ x,  const float* __restrict__ Wq,
                    const float* __restrict__ Wk, const float* __restrict__ Wv,
                    bf16_t* __restrict__ xb, bf16_t* __restrict__ wb)
{
    const int y = blockIdx.y;
    const float* src; bf16_t* dst;
    if (y < 16)      { src = x + (size_t)y * 262144; dst = xb + (size_t)y * 262144; }
    else if (y == 16){ src = Wq; dst = wb; }
    else if (y == 17){ src = Wk; dst = wb + 262144; }
    else             { src = Wv; dst = wb + 524288; }
    const int base = (blockIdx.x * 256 + threadIdx.x) * 16;
    const f32x8 a = *(const f32x8*)(src + base);
    const f32x8 b = *(const f32x8*)(src + base + 8);
    *(bf16x8*)(dst + base)     = __builtin_convertvector(a, bf16x8);
    *(bf16x8*)(dst + base + 8) = __builtin_convertvector(b, bf16x8);
}

// ---------------------------------------------------------------------------
// GEMM + bias + GELU.  C[m][n] = gelu( sum_k X[m][k]*W[n][k] + bias[n] )
//
// R7: TRUE double-buffered DMA pipeline (T3-minimum, m230-V0 ~682 TF class).
//  - 2x LDS buffers; DMA for tile kt+2 issued right after computing the
//    buffer it reuses; per-iter wait is COUNTED vmcnt(8/4) (never 0 in the
//    loop; vmcnt(0) only at the last tile). m233: the serial 2-phase drain
//    (R6) stalls ~72% — this amortizes it (R5<->R6 A/B: both serial forms
//    tied at ~same time, consistent with both sitting on that stall).
//  - Swizzle carried verbatim from R6 (verified: passed, conflicts-free
//    algebra same as flash's measured-0).
// MODE 0 (QKV, NTILE=128): A+B DMA, 8 loads/thread/tile, LDS 64KB (2/CU).
// MODE 1 (out, NTILE=64):  A DMA (4), B fp32 reg-staged in the issue slot
//    (B loads issued FIRST, so the compiler's wait for them leaves A's DMA
//    in flight), LDS 48KB (3/CU).
// ---------------------------------------------------------------------------
template<int MODE, int NTILE>
__global__ __launch_bounds__(256, 2)
void gemm_gelu_kernel(const bf16_t* __restrict__ Xb,
                      const bf16_t* __restrict__ Wb,   // MODE 0
                      const float*  __restrict__ Wf,   // MODE 1
                      const float*  __restrict__ Bq, const float* __restrict__ Bk,
                      const float*  __restrict__ Bv,
                      bf16_t* __restrict__ O0, bf16_t* __restrict__ O1,
                      bf16_t* __restrict__ O2, float* __restrict__ Of)
{
    constexpr int NTN = NTILE / 32;
    __shared__ __align__(16) bf16_t As[2][128 * 64];
    __shared__ __align__(16) bf16_t Bs[2][NTILE * 64];
    const int tid  = threadIdx.x;
    const int lane = tid & 63, w = tid >> 6, quad = lane >> 4, l15 = lane & 15;
    const int m0 = blockIdx.x * 128;
    int mat, n0;
    if (MODE == 0) { mat = blockIdx.y >> 2; n0 = (blockIdx.y & 3) * NTILE; }
    else           { mat = 0;               n0 = blockIdx.y * NTILE; }
    const bf16_t* W  = (MODE == 0) ? (Wb + (size_t)mat * 262144) : nullptr;
    const float*  Bi = (MODE == 1) ? Bq : (mat == 0 ? Bq : (mat == 1 ? Bk : Bv));

    const int wr = (w >> 1) * 64;            // wave row offset
    const int wc = (w & 1) * (NTILE / 2);    // wave col offset

    const int lrow  = lane >> 3;                       // 0..7 (row within 8-slab)
    const int lcsw  = (((lane & 7) ^ lrow) << 3);      // pre-swizzled col group
    const int srow  = tid >> 3, scol = (tid & 7) * 8;  // MODE1 B reg-staging
    const int cxg   = (l15 & 7) << 3;                  // read-side swizzle

    f32x4 acc[4][NTN];
#pragma unroll
    for (int a = 0; a < 4; ++a)
#pragma unroll
        for (int b = 0; b < NTN; ++b) acc[a][b] = f32x4{0.f, 0.f, 0.f, 0.f};

    // issue staging for tile kt into buffer buf
    auto issue = [&](int kt, int buf) {
        const int k0 = kt * 64;
        if (MODE == 1) {
            f32x8 wv[NTN];
#pragma unroll
            for (int it = 0; it < NTN; ++it) {
                const int r = it * 32 + srow;
                wv[it] = *(const f32x8*)(Wf + (size_t)(n0 + r) * EMBED + k0 + scol);
            }
#pragma unroll
            for (int it = 0; it < 4; ++it)
                gload16(Xb + (size_t)(m0 + it * 32 + w * 8 + lrow) * EMBED + k0 + lcsw,
                        &As[buf][(it * 32 + w * 8) * 64]);
#pragma unroll
            for (int it = 0; it < NTN; ++it) {
                const int r = it * 32 + srow;
                *(bf16x8*)(&Bs[buf][r * 64 + (scol ^ ((r & 7) << 3))]) =
                    __builtin_convertvector(wv[it], bf16x8);
            }
        } else {
#pragma unroll
            for (int it = 0; it < 4; ++it)
                gload16(Xb + (size_t)(m0 + it * 32 + w * 8 + lrow) * EMBED + k0 + lcsw,
                        &As[buf][(it * 32 + w * 8) * 64]);
#pragma unroll
            for (int it = 0; it < NTN; ++it)
                gload16(W + (size_t)(n0 + it * 32 + w * 8 + lrow) * EMBED + k0 + lcsw,
                        &Bs[buf][(it * 32 + w * 8) * 64]);
        }
    };

    // prologue: tiles 0 and 1 in flight
    issue(0, 0);
    issue(1, 1);

#pragma unroll 1
    for (int kt = 0; kt < 8; ++kt) {
        // counted wait: tile kt landed; tile kt+1's loads stay in flight
        if (kt == 7)           asm volatile("s_waitcnt vmcnt(0)" ::: "memory");
        else if (MODE == 0)    asm volatile("s_waitcnt vmcnt(8)" ::: "memory");
        else                   asm volatile("s_waitcnt vmcnt(4)" ::: "memory");
        barrier_nodrain();                 // + lgkm for MODE1 ds_writes
        const int cb = kt & 1;
        const bf16_t* Ab = As[cb];
        const bf16_t* Bb = Bs[cb];
#pragma unroll
        for (int ks = 0; ks < 2; ++ks) {
            const int ko = (ks * 4 + quad) * 8;
            const int kos = ko ^ cxg;
            bf16x8 av[4], bv[NTN];
#pragma unroll
            for (int mt = 0; mt < 4; ++mt)
                av[mt] = *(const bf16x8*)(Ab + (wr + mt * 16 + l15) * 64 + kos);
#pragma unroll
            for (int nt = 0; nt < NTN; ++nt)
                bv[nt] = *(const bf16x8*)(Bb + (wc + nt * 16 + l15) * 64 + kos);
#pragma unroll
            for (int mt = 0; mt < 4; ++mt)
#pragma unroll
                for (int nt = 0; nt < NTN; ++nt)
                    acc[mt][nt] = mfma16(av[mt], bv[nt], acc[mt][nt]);
        }
        barrier_plain();                   // readers of buf cb done
        if (kt + 2 < 8) issue(kt + 2, cb); // refill the buffer just drained
    }

    // epilogue (C/D layout: col=l15, row=quad*4+i)
    float biasv[NTN];
#pragma unroll
    for (int nt = 0; nt < NTN; ++nt)
        biasv[nt] = Bi[n0 + wc + nt * 16 + l15];
#pragma unroll
    for (int mt = 0; mt < 4; ++mt) {
        const int mb = m0 + wr + mt * 16 + quad * 4;
        const int bb = mb >> 11, s0 = mb & (SEQ - 1);
#pragma unroll
        for (int nt = 0; nt < NTN; ++nt) {
            const int fc = n0 + wc + nt * 16 + l15;
            const int h = fc >> 6, d = fc & 63;
            float vv[4];
#pragma unroll
            for (int i = 0; i < 4; ++i) vv[i] = gelu_f(acc[mt][nt][i] + biasv[nt]);
            if (MODE == 1) {
#pragma unroll
                for (int i = 0; i < 4; ++i) Of[(size_t)(mb + i) * EMBED + fc] = vv[i];
            } else if (mat == 0) {
#pragma unroll
                for (int i = 0; i < 4; ++i)
                    O0[(((size_t)(bb * NH + h)) * SEQ + s0 + i) * HD + d] = (bf16_t)(vv[i] * SCQ);
            } else if (mat == 1) {
#pragma unroll
                for (int i = 0; i < 4; ++i)
                    O1[(((size_t)(bb * NH + h)) * SEQ + s0 + i) * HD + d] = (bf16_t)vv[i];
            } else {
                bf16x4 pk;
#pragma unroll
                for (int i = 0; i < 4; ++i) pk[i] = (bf16_t)vv[i];
                *(bf16x4*)(O2 + ((size_t)(bb * NH + h) * HD + d) * SEQ + s0) = pk;
            }
        }
    }
}

// ---------------------------------------------------------------------------
// Flash attention — UNCHANGED from R5/R6 (68.4 µs, conflicts 0, T12 in-reg
// P). R0-R6: invariant to occupancy/LDS-BW/conflicts/drains/prefetch.
// ---------------------------------------------------------------------------
#define FA_ITER(T, BUF, KR0, KR1, VR0, VR1)                                   \
    do {                                                                      \
        if ((T) + 1 < 32) {                                                   \
            bf16_t* Kn = Ks[(BUF) ^ 1];                                       \
            bf16_t* Vn = Vs[(BUF) ^ 1];                                       \
            *(bf16x8*)(Kn + sA)        = KR0;                                 \
            *(bf16x8*)(Kn + sA + 2048) = KR1;                                 \
            *(bf16x8*)(Vn + sA)        = VR0;                                 \
            *(bf16x8*)(Vn + sA + 2048) = VR1;                                 \
        }                                                                     \
        if ((T) + 3 < 32) {                                                   \
            const int kv = ((T) + 3) * 64;                                    \
            KR0 = *(const bf16x8*)(K + baseQK + (size_t)(kv + r0) * HD + c0); \
            KR1 = *(const bf16x8*)(K + baseQK + (size_t)(kv + r0 + 32) * HD + c0); \
            VR0 = *(const bf16x8*)(Vt + baseV + (size_t)r0 * SEQ + kv + c0);  \
            VR1 = *(const bf16x8*)(Vt + baseV + (size_t)(r0 + 32) * SEQ + kv + c0); \
        }                                                                     \
        const bf16_t* Kb = Ks[(BUF)];                                         \
        const bf16_t* Vb = Vs[(BUF)];                                         \
        f32x4 sf[4];                                                          \
        _Pragma("unroll")                                                     \
        for (int jt = 0; jt < 4; ++jt) sf[jt] = f32x4{0.f, 0.f, 0.f, 0.f};    \
        __builtin_amdgcn_s_setprio(1);                                        \
        _Pragma("unroll")                                                     \
        for (int ks = 0; ks < 2; ++ks) {                                      \
            const int ko = (ks * 32 + quad * 8) ^ cx;                         \
            _Pragma("unroll")                                                 \
            for (int jt = 0; jt < 4; ++jt) {                                  \
                const bf16x8 a = *(const bf16x8*)(Kb + ((jt * 16 + l15) << 6) + ko); \
                sf[jt] = mfma16(a, qf[ks], sf[jt]);                           \
            }                                                                 \
        }                                                                     \
        __builtin_amdgcn_s_setprio(0);                                        \
        u32 w0[4], w1[4];                                                     \
        _Pragma("unroll")                                                     \
        for (int jt = 0; jt < 4; ++jt) {                                      \
            _Pragma("unroll")                                                 \
            for (int i = 0; i < 4; ++i) sf[jt][i] = exp2f(sf[jt][i]);         \
            lacc += sf[jt];                                                   \
            w0[jt] = cvtpk_bf16(sf[jt][0], sf[jt][1]);                        \
            w1[jt] = cvtpk_bf16(sf[jt][2], sf[jt][3]);                        \
        }                                                                     \
        swap32(w0[0], w0[1]); swap16(w0[0], w0[1]);                           \
        swap32(w1[0], w1[1]); swap16(w1[0], w1[1]);                           \
        swap32(w0[2], w0[3]); swap16(w0[2], w0[3]);                           \
        swap32(w1[2], w1[3]); swap16(w1[2], w1[3]);                           \
        const u32x4 pq0 = u32x4{w0[0], w1[0], w0[1], w1[1]};                  \
        const u32x4 pq1 = u32x4{w0[2], w1[2], w0[3], w1[3]};                  \
        const bf16x8 pa0 = __builtin_bit_cast(bf16x8, pq0);                   \
        const bf16x8 pa1 = __builtin_bit_cast(bf16x8, pq1);                   \
        __builtin_amdgcn_s_setprio(1);                                        \
        _Pragma("unroll")                                                     \
        for (int c = 0; c < 2; ++c) {                                         \
            const int ko = (c * 32 + quad * 8) ^ cx;                          \
            const bf16x8 pa = c ? pa1 : pa0;                                  \
            _Pragma("unroll")                                                 \
            for (int nt = 0; nt < 4; ++nt) {                                  \
                const bf16x8 b = *(const bf16x8*)(Vb + ((nt * 16 + l15) << 6) + ko); \
                oacc[nt] = mfma16(pa, b, oacc[nt]);                           \
            }                                                                 \
        }                                                                     \
        __builtin_amdgcn_s_setprio(0);                                        \
        if ((T) < 31) barrier_nodrain();                                      \
    } while (0)

__global__ __launch_bounds__(256, 4)
void flash_attn_kernel(const bf16_t* __restrict__ Q,
                       const bf16_t* __restrict__ K,
                       const bf16_t* __restrict__ Vt,
                       bf16_t* __restrict__ Og)
{
    __shared__ __align__(16) bf16_t Ks[2][64 * 64];
    __shared__ __align__(16) bf16_t Vs[2][64 * 64];

    const int tid  = threadIdx.x;
    const int lane = tid & 63, w = tid >> 6, quad = lane >> 4, l15 = lane & 15;
    const int bh = blockIdx.y;
    const int q0 = blockIdx.x * 64;
    const size_t baseQK = (size_t)bh * SEQ * HD;
    const size_t baseV  = (size_t)bh * HD * SEQ;
    const int wm = w * 16;
    const int cx = (l15 & 7) << 3;

    bf16x8 qf[2];
#pragma unroll
    for (int ks = 0; ks < 2; ++ks)
        qf[ks] = *(const bf16x8*)(Q + baseQK + (size_t)(q0 + wm + l15) * HD + ks * 32 + quad * 8);

    f32x4 lacc = f32x4{0.f, 0.f, 0.f, 0.f};
    f32x4 oacc[4];
#pragma unroll
    for (int nt = 0; nt < 4; ++nt) oacc[nt] = f32x4{0.f, 0.f, 0.f, 0.f};

    const int r0 = tid >> 3, c0 = (tid & 7) * 8;
    const int sA = (r0 << 6) + (c0 ^ ((r0 & 7) << 3));

    bf16x8 kA0, kA1, vA0, vA1;
    bf16x8 kB0, kB1, vB0, vB1;

    kA0 = *(const bf16x8*)(K + baseQK + (size_t)r0 * HD + c0);
    kA1 = *(const bf16x8*)(K + baseQK + (size_t)(r0 + 32) * HD + c0);
    vA0 = *(const bf16x8*)(Vt + baseV + (size_t)r0 * SEQ + c0);
    vA1 = *(const bf16x8*)(Vt + baseV + (size_t)(r0 + 32) * SEQ + c0);
    *(bf16x8*)(Ks[0] + sA)        = kA0;
    *(bf16x8*)(Ks[0] + sA + 2048) = kA1;
    *(bf16x8*)(Vs[0] + sA)        = vA0;
    *(bf16x8*)(Vs[0] + sA + 2048) = vA1;
    kB0 = *(const bf16x8*)(K + baseQK + (size_t)(64 + r0) * HD + c0);
    kB1 = *(const bf16x8*)(K + baseQK + (size_t)(64 + r0 + 32) * HD + c0);
    vB0 = *(const bf16x8*)(Vt + baseV + (size_t)r0 * SEQ + 64 + c0);
    vB1 = *(const bf16x8*)(Vt + baseV + (size_t)(r0 + 32) * SEQ + 64 + c0);
    kA0 = *(const bf16x8*)(K + baseQK + (size_t)(128 + r0) * HD + c0);
    kA1 = *(const bf16x8*)(K + baseQK + (size_t)(128 + r0 + 32) * HD + c0);
    vA0 = *(const bf16x8*)(Vt + baseV + (size_t)r0 * SEQ + 128 + c0);
    vA1 = *(const bf16x8*)(Vt + baseV + (size_t)(r0 + 32) * SEQ + 128 + c0);
    barrier_nodrain();

#pragma unroll 1
    for (int tt = 0; tt < 32; tt += 2) {
        FA_ITER(tt,     0, kB0, kB1, vB0, vB1);
        FA_ITER(tt + 1, 1, kA0, kA1, vA0, vA1);
    }

    const int bidx = bh >> 3, h = bh & 7;
    float rs = (lacc[0] + lacc[1]) + (lacc[2] + lacc[3]);
    rs += __shfl_xor(rs, 16);
    rs += __shfl_xor(rs, 32);
    float lf[4];
#pragma unroll
    for (int i = 0; i < 4; ++i)
        lf[i] = __shfl(rs, (lane & 48) | (quad * 4 + i));
#pragma unroll
    for (int nt = 0; nt < 4; ++nt)
#pragma unroll
        for (int i = 0; i < 4; ++i) {
            const int s = q0 + wm + quad * 4 + i;
            const int d = nt * 16 + l15;
            Og[((size_t)(bidx * SEQ + s)) * EMBED + h * HD + d] =
                (bf16_t)(oacc[nt][i] / lf[i]);
        }
}

extern "C" void kernel_launch(void* const* d_in, const int* in_sizes, int n_in,
                              void* d_out, int out_size, void* d_ws, size_t ws_size,
                              hipStream_t stream)
{
    const float* x  = (const float*)d_in[0];
    const float* Wq = (const float*)d_in[1];
    const float* bq = (const float*)d_in[2];
    const float* Wk = (const float*)d_in[3];
    const float* bk = (const float*)d_in[4];
    const float* Wv = (const float*)d_in[5];
    const float* bv = (const float*)d_in[6];
    const float* Wo = (const float*)d_in[7];
    const float* bo = (const float*)d_in[8];
    float* out = (float*)d_out;

    const size_t NE = (size_t)MTOT * EMBED;   // 4,194,304 elems
    bf16_t* xb  = (bf16_t*)d_out;
    bf16_t* Qw  = (bf16_t*)d_out + NE;
    bf16_t* Kw  = (bf16_t*)d_ws;
    bf16_t* Vtw = Kw + NE;
    bf16_t* Ow  = Vtw + NE;
    bf16_t* Wb  = Ow;

    convert_kernel<<<dim3(64, 19), 256, 0, stream>>>(x, Wq, Wk, Wv, xb, Wb);
    gemm_gelu_kernel<0, 128><<<dim3(64, 12), 256, 0, stream>>>(
        xb, Wb, nullptr, bq, bk, bv, Qw, Kw, Vtw, nullptr);
    flash_attn_kernel<<<dim3(32, 32), 256, 0, stream>>>(Qw, Kw, Vtw, Ow);
    gemm_gelu_kernel<1, 64><<<dim3(64, 8), 256, 0, stream>>>(
        Ow, nullptr, Wo, bo, nullptr, nullptr, nullptr, nullptr, nullptr, out);
}

// Round 8
// 179.361 us; speedup vs baseline: 1.0715x; 1.0715x over previous
//
#include <hip/hip_runtime.h>
#include <hip/hip_bf16.h>

typedef __bf16 bf16_t;
typedef __bf16 bf16x4 __attribute__((ext_vector_type(4)));
typedef __bf16 bf16x8 __attribute__((ext_vector_type(8)));
typedef float  f32x4  __attribute__((ext_vector_type(4)));
typedef float  f32x8  __attribute__((ext_vector_type(8)));
typedef unsigned int u32;
typedef u32 u32x4 __attribute__((ext_vector_type(4)));

#define EMBED 512
#define NH    8
#define HD    64
#define SEQ   2048
#define MTOT  8192
#define SCQ   0.18033688011112042f   // log2(e) / sqrt(64), folded into Q

__device__ __forceinline__ float gelu_f(float x) {
    return 0.5f * x * (1.0f + erff(x * 0.7071067811865475f));
}

__device__ __forceinline__ f32x4 mfma16(bf16x8 a, bf16x8 b, f32x4 c) {
    return __builtin_amdgcn_mfma_f32_16x16x32_bf16(a, b, c, 0, 0, 0);
}

// Raw barrier: LDS-write visibility only (lgkmcnt(0)), NO vmcnt drain —
// global prefetch loads stay in flight across the barrier; the compiler
// emits counted vmcnt waits at the dependent use.
__device__ __forceinline__ void barrier_nodrain() {
    asm volatile("s_waitcnt lgkmcnt(0)" ::: "memory");
    __builtin_amdgcn_s_barrier();
    asm volatile("" ::: "memory");
}

// T12 primitives (flash): pack 2 f32 -> 2 bf16, cross-lane register swaps.
__device__ __forceinline__ u32 cvtpk_bf16(float lo, float hi) {
    u32 r;
    asm("v_cvt_pk_bf16_f32 %0, %1, %2" : "=v"(r) : "v"(lo), "v"(hi));
    return r;
}
__device__ __forceinline__ void swap32(u32& a, u32& b) {
    asm volatile("v_permlane32_swap_b32 %0, %1" : "+v"(a), "+v"(b));
}
__device__ __forceinline__ void swap16(u32& a, u32& b) {
    asm volatile("v_permlane16_swap_b32 %0, %1" : "+v"(a), "+v"(b));
}

// ---------------------------------------------------------------------------
// GEMM + bias + GELU.  C[m][n] = gelu( sum_k X[m][k]*W[n][k] + bias[n] )
//
// R8: revert to the R5 structure (session best, 179.1): reg-staging,
// padded-72 LDS, nodrain barriers, (256,3). The R5/R6/R7 triple A/B showed
// staging/pipeline micro-structure is NOT the lever for this K=512 shape
// (all within ±5%), so take the structure with the best measured total.
//
// NEW in R8: the fp32->bf16 convert kernel is FUSED here (deleted as a
// separate launch). MODE 0 reads x and Wq/Wk/Wv as fp32 directly:
//  - A (x, 33 MB, L3-resident, needs latency hiding): f32x8 register
//    prefetch across the barrier, convert at ds_write (R5's A pattern).
//  - W (1.5 MB, L2-hot after first blocks): load+convert+write INLINE in
//    the staging phase (short L2 latency, keeps in-flight VGPRs ~150 so
//    (256,3) holds without spills).
// MODE 1 (out-proj): A bf16 prefetched, Wo fp32 inline — same skeleton.
// ---------------------------------------------------------------------------
template<int MODE, int NTILE>
__global__ __launch_bounds__(256, 3)
void gemm_gelu_kernel(const void*  __restrict__ Xp,
                      const float* __restrict__ W0, const float* __restrict__ W1,
                      const float* __restrict__ W2,
                      const float* __restrict__ Bq, const float* __restrict__ Bk,
                      const float* __restrict__ Bv,
                      bf16_t* __restrict__ O0, bf16_t* __restrict__ O1,
                      bf16_t* __restrict__ O2, float* __restrict__ Of)
{
    constexpr int NTN = NTILE / 32;   // B-staging iters/thr
    __shared__ __align__(16) bf16_t As[128 * 72];
    __shared__ __align__(16) bf16_t Bs[NTILE * 72];
    const int tid  = threadIdx.x;
    const int lane = tid & 63, w = tid >> 6, quad = lane >> 4, l15 = lane & 15;
    const int m0 = blockIdx.x * 128;
    int mat, n0;
    if (MODE == 0) { mat = blockIdx.y >> 2; n0 = (blockIdx.y & 3) * NTILE; }
    else           { mat = 0;               n0 = blockIdx.y * NTILE; }
    const float* W  = (MODE == 0) ? (mat == 0 ? W0 : (mat == 1 ? W1 : W2)) : W0;
    const float* Bi = (MODE == 1) ? Bq : (mat == 0 ? Bq : (mat == 1 ? Bk : Bv));
    const float*  Xf = (const float*)Xp;    // MODE 0
    const bf16_t* Xb = (const bf16_t*)Xp;   // MODE 1

    const int wr = (w >> 1) * 64;            // wave row offset
    const int wc = (w & 1) * (NTILE / 2);    // wave col offset

    const int srow = tid >> 3, scol = (tid & 7) * 8;

    f32x4 acc[4][NTN];
#pragma unroll
    for (int a = 0; a < 4; ++a)
#pragma unroll
        for (int b = 0; b < NTN; ++b) acc[a][b] = f32x4{0.f, 0.f, 0.f, 0.f};

    f32x8  xpf[4];   // MODE 0 A prefetch (fp32)
    bf16x8 xpb[4];   // MODE 1 A prefetch (bf16)

    // prologue: A tile 0 -> regs
#pragma unroll
    for (int it = 0; it < 4; ++it) {
        const size_t r = (size_t)(m0 + it * 32 + srow);
        if (MODE == 0) xpf[it] = *(const f32x8*)(Xf + r * EMBED + scol);
        else           xpb[it] = *(const bf16x8*)(Xb + r * EMBED + scol);
    }

#pragma unroll 1
    for (int kt = 0; kt < 8; ++kt) {
        const int k0 = kt * 64;
        barrier_nodrain();   // readers of As/Bs (iter kt-1) are done
        // A: write prefetched regs (convert if fp32)
#pragma unroll
        for (int it = 0; it < 4; ++it) {
            if (MODE == 0)
                *(bf16x8*)(As + (it * 32 + srow) * 72 + scol) =
                    __builtin_convertvector(xpf[it], bf16x8);
            else
                *(bf16x8*)(As + (it * 32 + srow) * 72 + scol) = xpb[it];
        }
        // W: inline load+convert+write (L2-hot; no cross-barrier regs)
#pragma unroll
        for (int it = 0; it < NTN; ++it) {
            const int r = it * 32 + srow;
            const f32x8 wv = *(const f32x8*)(W + (size_t)(n0 + r) * EMBED + k0 + scol);
            *(bf16x8*)(Bs + r * 72 + scol) = __builtin_convertvector(wv, bf16x8);
        }
        // A: prefetch tile kt+1
        if (kt < 7) {
            const int k1 = k0 + 64;
#pragma unroll
            for (int it = 0; it < 4; ++it) {
                const size_t r = (size_t)(m0 + it * 32 + srow);
                if (MODE == 0) xpf[it] = *(const f32x8*)(Xf + r * EMBED + k1 + scol);
                else           xpb[it] = *(const bf16x8*)(Xb + r * EMBED + k1 + scol);
            }
        }
        barrier_nodrain();   // As/Bs writes visible to all waves
#pragma unroll
        for (int ks = 0; ks < 2; ++ks) {
            const int ko = (ks * 4 + quad) * 8;
            bf16x8 av[4], bv[NTN];
#pragma unroll
            for (int mt = 0; mt < 4; ++mt)
                av[mt] = *(const bf16x8*)(As + (wr + mt * 16 + l15) * 72 + ko);
#pragma unroll
            for (int nt = 0; nt < NTN; ++nt)
                bv[nt] = *(const bf16x8*)(Bs + (wc + nt * 16 + l15) * 72 + ko);
#pragma unroll
            for (int mt = 0; mt < 4; ++mt)
#pragma unroll
                for (int nt = 0; nt < NTN; ++nt)
                    acc[mt][nt] = mfma16(av[mt], bv[nt], acc[mt][nt]);
        }
    }

    // epilogue (C/D layout: col=l15, row=quad*4+i)
    float biasv[NTN];
#pragma unroll
    for (int nt = 0; nt < NTN; ++nt)
        biasv[nt] = Bi[n0 + wc + nt * 16 + l15];
#pragma unroll
    for (int mt = 0; mt < 4; ++mt) {
        const int mb = m0 + wr + mt * 16 + quad * 4;
        const int bb = mb >> 11, s0 = mb & (SEQ - 1);
#pragma unroll
        for (int nt = 0; nt < NTN; ++nt) {
            const int fc = n0 + wc + nt * 16 + l15;
            const int h = fc >> 6, d = fc & 63;
            float vv[4];
#pragma unroll
            for (int i = 0; i < 4; ++i) vv[i] = gelu_f(acc[mt][nt][i] + biasv[nt]);
            if (MODE == 1) {
#pragma unroll
                for (int i = 0; i < 4; ++i) Of[(size_t)(mb + i) * EMBED + fc] = vv[i];
            } else if (mat == 0) {
#pragma unroll
                for (int i = 0; i < 4; ++i)
                    O0[(((size_t)(bb * NH + h)) * SEQ + s0 + i) * HD + d] = (bf16_t)(vv[i] * SCQ);
            } else if (mat == 1) {
#pragma unroll
                for (int i = 0; i < 4; ++i)
                    O1[(((size_t)(bb * NH + h)) * SEQ + s0 + i) * HD + d] = (bf16_t)vv[i];
            } else {
                bf16x4 pk;
#pragma unroll
                for (int i = 0; i < 4; ++i) pk[i] = (bf16_t)vv[i];
                *(bf16x4*)(O2 + ((size_t)(bb * NH + h) * HD + d) * SEQ + s0) = pk;
            }
        }
    }
}

// ---------------------------------------------------------------------------
// Flash attention — UNCHANGED from R5/R6/R7 (67.4-68.4 µs stable, conflicts
// 0, T12 in-reg P). R0-R7: invariant to occupancy/LDS-BW/conflicts/drains.
// ---------------------------------------------------------------------------
#define FA_ITER(T, BUF, KR0, KR1, VR0, VR1)                                   \
    do {                                                                      \
        if ((T) + 1 < 32) {                                                   \
            bf16_t* Kn = Ks[(BUF) ^ 1];                                       \
            bf16_t* Vn = Vs[(BUF) ^ 1];                                       \
            *(bf16x8*)(Kn + sA)        = KR0;                                 \
            *(bf16x8*)(Kn + sA + 2048) = KR1;                                 \
            *(bf16x8*)(Vn + sA)        = VR0;                                 \
            *(bf16x8*)(Vn + sA + 2048) = VR1;                                 \
        }                                                                     \
        if ((T) + 3 < 32) {                                                   \
            const int kv = ((T) + 3) * 64;                                    \
            KR0 = *(const bf16x8*)(K + baseQK + (size_t)(kv + r0) * HD + c0); \
            KR1 = *(const bf16x8*)(K + baseQK + (size_t)(kv + r0 + 32) * HD + c0); \
            VR0 = *(const bf16x8*)(Vt + baseV + (size_t)r0 * SEQ + kv + c0);  \
            VR1 = *(const bf16x8*)(Vt + baseV + (size_t)(r0 + 32) * SEQ + kv + c0); \
        }                                                                     \
        const bf16_t* Kb = Ks[(BUF)];                                         \
        const bf16_t* Vb = Vs[(BUF)];                                         \
        f32x4 sf[4];                                                          \
        _Pragma("unroll")                                                     \
        for (int jt = 0; jt < 4; ++jt) sf[jt] = f32x4{0.f, 0.f, 0.f, 0.f};    \
        __builtin_amdgcn_s_setprio(1);                                        \
        _Pragma("unroll")                                                     \
        for (int ks = 0; ks < 2; ++ks) {                                      \
            const int ko = (ks * 32 + quad * 8) ^ cx;                         \
            _Pragma("unroll")                                                 \
            for (int jt = 0; jt < 4; ++jt) {                                  \
                const bf16x8 a = *(const bf16x8*)(Kb + ((jt * 16 + l15) << 6) + ko); \
                sf[jt] = mfma16(a, qf[ks], sf[jt]);                           \
            }                                                                 \
        }                                                                     \
        __builtin_amdgcn_s_setprio(0);                                        \
        u32 w0[4], w1[4];                                                     \
        _Pragma("unroll")                                                     \
        for (int jt = 0; jt < 4; ++jt) {                                      \
            _Pragma("unroll")                                                 \
            for (int i = 0; i < 4; ++i) sf[jt][i] = exp2f(sf[jt][i]);         \
            lacc += sf[jt];                                                   \
            w0[jt] = cvtpk_bf16(sf[jt][0], sf[jt][1]);                        \
            w1[jt] = cvtpk_bf16(sf[jt][2], sf[jt][3]);                        \
        }                                                                     \
        swap32(w0[0], w0[1]); swap16(w0[0], w0[1]);                           \
        swap32(w1[0], w1[1]); swap16(w1[0], w1[1]);                           \
        swap32(w0[2], w0[3]); swap16(w0[2], w0[3]);                           \
        swap32(w1[2], w1[3]); swap16(w1[2], w1[3]);                           \
        const u32x4 pq0 = u32x4{w0[0], w1[0], w0[1], w1[1]};                  \
        const u32x4 pq1 = u32x4{w0[2], w1[2], w0[3], w1[3]};                  \
        const bf16x8 pa0 = __builtin_bit_cast(bf16x8, pq0);                   \
        const bf16x8 pa1 = __builtin_bit_cast(bf16x8, pq1);                   \
        __builtin_amdgcn_s_setprio(1);                                        \
        _Pragma("unroll")                                                     \
        for (int c = 0; c < 2; ++c) {                                         \
            const int ko = (c * 32 + quad * 8) ^ cx;                          \
            const bf16x8 pa = c ? pa1 : pa0;                                  \
            _Pragma("unroll")                                                 \
            for (int nt = 0; nt < 4; ++nt) {                                  \
                const bf16x8 b = *(const bf16x8*)(Vb + ((nt * 16 + l15) << 6) + ko); \
                oacc[nt] = mfma16(pa, b, oacc[nt]);                           \
            }                                                                 \
        }                                                                     \
        __builtin_amdgcn_s_setprio(0);                                        \
        if ((T) < 31) barrier_nodrain();                                      \
    } while (0)

__global__ __launch_bounds__(256, 4)
void flash_attn_kernel(const bf16_t* __restrict__ Q,
                       const bf16_t* __restrict__ K,
                       const bf16_t* __restrict__ Vt,
                       bf16_t* __restrict__ Og)
{
    __shared__ __align__(16) bf16_t Ks[2][64 * 64];
    __shared__ __align__(16) bf16_t Vs[2][64 * 64];

    const int tid  = threadIdx.x;
    const int lane = tid & 63, w = tid >> 6, quad = lane >> 4, l15 = lane & 15;
    const int bh = blockIdx.y;
    const int q0 = blockIdx.x * 64;
    const size_t baseQK = (size_t)bh * SEQ * HD;
    const size_t baseV  = (size_t)bh * HD * SEQ;
    const int wm = w * 16;
    const int cx = (l15 & 7) << 3;

    bf16x8 qf[2];
#pragma unroll
    for (int ks = 0; ks < 2; ++ks)
        qf[ks] = *(const bf16x8*)(Q + baseQK + (size_t)(q0 + wm + l15) * HD + ks * 32 + quad * 8);

    f32x4 lacc = f32x4{0.f, 0.f, 0.f, 0.f};
    f32x4 oacc[4];
#pragma unroll
    for (int nt = 0; nt < 4; ++nt) oacc[nt] = f32x4{0.f, 0.f, 0.f, 0.f};

    const int r0 = tid >> 3, c0 = (tid & 7) * 8;
    const int sA = (r0 << 6) + (c0 ^ ((r0 & 7) << 3));

    bf16x8 kA0, kA1, vA0, vA1;
    bf16x8 kB0, kB1, vB0, vB1;

    kA0 = *(const bf16x8*)(K + baseQK + (size_t)r0 * HD + c0);
    kA1 = *(const bf16x8*)(K + baseQK + (size_t)(r0 + 32) * HD + c0);
    vA0 = *(const bf16x8*)(Vt + baseV + (size_t)r0 * SEQ + c0);
    vA1 = *(const bf16x8*)(Vt + baseV + (size_t)(r0 + 32) * SEQ + c0);
    *(bf16x8*)(Ks[0] + sA)        = kA0;
    *(bf16x8*)(Ks[0] + sA + 2048) = kA1;
    *(bf16x8*)(Vs[0] + sA)        = vA0;
    *(bf16x8*)(Vs[0] + sA + 2048) = vA1;
    kB0 = *(const bf16x8*)(K + baseQK + (size_t)(64 + r0) * HD + c0);
    kB1 = *(const bf16x8*)(K + baseQK + (size_t)(64 + r0 + 32) * HD + c0);
    vB0 = *(const bf16x8*)(Vt + baseV + (size_t)r0 * SEQ + 64 + c0);
    vB1 = *(const bf16x8*)(Vt + baseV + (size_t)(r0 + 32) * SEQ + 64 + c0);
    kA0 = *(const bf16x8*)(K + baseQK + (size_t)(128 + r0) * HD + c0);
    kA1 = *(const bf16x8*)(K + baseQK + (size_t)(128 + r0 + 32) * HD + c0);
    vA0 = *(const bf16x8*)(Vt + baseV + (size_t)r0 * SEQ + 128 + c0);
    vA1 = *(const bf16x8*)(Vt + baseV + (size_t)(r0 + 32) * SEQ + 128 + c0);
    barrier_nodrain();

#pragma unroll 1
    for (int tt = 0; tt < 32; tt += 2) {
        FA_ITER(tt,     0, kB0, kB1, vB0, vB1);
        FA_ITER(tt + 1, 1, kA0, kA1, vA0, vA1);
    }

    const int bidx = bh >> 3, h = bh & 7;
    float rs = (lacc[0] + lacc[1]) + (lacc[2] + lacc[3]);
    rs += __shfl_xor(rs, 16);
    rs += __shfl_xor(rs, 32);
    float lf[4];
#pragma unroll
    for (int i = 0; i < 4; ++i)
        lf[i] = __shfl(rs, (lane & 48) | (quad * 4 + i));
#pragma unroll
    for (int nt = 0; nt < 4; ++nt)
#pragma unroll
        for (int i = 0; i < 4; ++i) {
            const int s = q0 + wm + quad * 4 + i;
            const int d = nt * 16 + l15;
            Og[((size_t)(bidx * SEQ + s)) * EMBED + h * HD + d] =
                (bf16_t)(oacc[nt][i] / lf[i]);
        }
}

extern "C" void kernel_launch(void* const* d_in, const int* in_sizes, int n_in,
                              void* d_out, int out_size, void* d_ws, size_t ws_size,
                              hipStream_t stream)
{
    const float* x  = (const float*)d_in[0];
    const float* Wq = (const float*)d_in[1];
    const float* bq = (const float*)d_in[2];
    const float* Wk = (const float*)d_in[3];
    const float* bk = (const float*)d_in[4];
    const float* Wv = (const float*)d_in[5];
    const float* bv = (const float*)d_in[6];
    const float* Wo = (const float*)d_in[7];
    const float* bo = (const float*)d_in[8];
    float* out = (float*)d_out;

    const size_t NE = (size_t)MTOT * EMBED;   // 4,194,304 elems
    // Layout: Qw in d_out's 2nd half (dead before final fp32 out overwrite);
    // Kw / Vtw / Ow in ws (24 MB as before). No xb / Wb anymore (convert
    // fused into the QKV GEMM).
    bf16_t* Qw  = (bf16_t*)d_out + NE;
    bf16_t* Kw  = (bf16_t*)d_ws;
    bf16_t* Vtw = Kw + NE;
    bf16_t* Ow  = Vtw + NE;

    gemm_gelu_kernel<0, 128><<<dim3(64, 12), 256, 0, stream>>>(
        x, Wq, Wk, Wv, bq, bk, bv, Qw, Kw, Vtw, nullptr);
    flash_attn_kernel<<<dim3(32, 32), 256, 0, stream>>>(Qw, Kw, Vtw, Ow);
    gemm_gelu_kernel<1, 64><<<dim3(64, 8), 256, 0, stream>>>(
        Ow, Wo, nullptr, nullptr, bo, nullptr, nullptr,
        nullptr, nullptr, nullptr, out);
}